// Round 10
// baseline (1079.899 us; speedup 1.0000x reference)
//
#include <hip/hip_runtime.h>
#include <cstdint>
#include <cstddef>

#define BATCH 8
#define SEQ   4096
#define DS    512
#define JPL   8              // states per lane (64 lanes * 8 = 512)
#define BLK   8              // time steps per LDS block
#define NBLK  (SEQ / BLK)    // 512
#define LN_EPS 1e-5f

typedef float v2f __attribute__((ext_vector_type(2)));
typedef float v4f __attribute__((ext_vector_type(4)));

static __device__ __forceinline__ v2f lo2(v4f x) { return __builtin_shufflevector(x, x, 0, 1); }
static __device__ __forceinline__ v2f hi2(v4f x) { return __builtin_shufflevector(x, x, 2, 3); }

// ---- DPP wave64 reduction: row_shr 1/2/4/8, row_bcast15/31 -> lane 63 ----
template <int CTRL>
__device__ __forceinline__ float dpp_add(float v) {
  int t = __builtin_amdgcn_update_dpp(0, __builtin_bit_cast(int, v), CTRL, 0xF, 0xF, true);
  return v + __builtin_bit_cast(float, t);
}
__device__ __forceinline__ float wave_sum64(float v) {
  v = dpp_add<0x111>(v);
  v = dpp_add<0x112>(v);
  v = dpp_add<0x114>(v);
  v = dpp_add<0x118>(v);
  v = dpp_add<0x142>(v);
  v = dpp_add<0x143>(v);
  return v;  // valid in lane 63
}
__device__ __forceinline__ float bcast63(float v) {
  return __builtin_bit_cast(float, __builtin_amdgcn_readlane(__builtin_bit_cast(int, v), 63));
}

// intra-lane trees over v2f[4]
__device__ __forceinline__ float t4s(const v2f* a) {
  v2f s = (a[0] + a[1]) + (a[2] + a[3]);
  return s.x + s.y;
}
__device__ __forceinline__ float t4m(const v2f* a, const v2f* b) {
  v2f s = a[0] * b[0];
  s = __builtin_elementwise_fma(a[1], b[1], s);
  v2f r = a[2] * b[2];
  r = __builtin_elementwise_fma(a[3], b[3], r);
  v2f q = s + r;
  return q.x + q.y;
}

// async HBM -> LDS: per-lane 16B from g, LDS dest = uniform base + lane*16
__device__ __forceinline__ void ld16(const float* g, float* l) {
  __builtin_amdgcn_global_load_lds(
      (const __attribute__((address_space(1))) void*)g,
      (__attribute__((address_space(3))) void*)l, 16, 0, 0);
}

// ---------------- factored-recurrence scan: 3 waves per batch ---------------
// hr_{t+1} = inv_t*g_t + w_t ;  g = aw(x)tv (post-mu, pre-inv), w = ab(x)rs + bd(x)x_{t+1}
// S1_{t+1} = inv*Sg + Sw ; S2_{t+1} = inv^2*Sgg + 2inv*Sgw + Sww
// -> rsqrt + all post-inv vector levels OFF the serial cycle; w-chains issue pre-mu.
// wave 0: consumer. wave 1: DMA x (2 ahead, 4-deep X, dma-first) + out-writes.
// wave 2: rg tiles + sum(c*bias*rg) (R1 form). Plain __syncthreads everywhere.
__global__ __launch_bounds__(192, 1) void ssm_scan(
    const float* __restrict__ x, const float* __restrict__ vol,
    const float* __restrict__ llr, const float* __restrict__ logb,
    const float* __restrict__ cvec, const float* __restrict__ lstp,
    const float* __restrict__ vgat, const float* __restrict__ lnw,
    const float* __restrict__ lnb, const float* __restrict__ alph,
    const float* __restrict__ logd, float* __restrict__ out)
{
  __shared__ __attribute__((aligned(16))) float X[4][4096];          // 64KB, 4-deep
  __shared__ __attribute__((aligned(16))) float G0[4096], G1[4096];  // rg tiles
  __shared__ __attribute__((aligned(16))) float SC0[512], SC1[512];  // readout partials
  __shared__ __attribute__((aligned(16))) float SB0[512], SB1[512];  // sum(c*bias*rg)

  const int b    = blockIdx.x;
  const int lane = threadIdx.x & 63;
  const int wid  = threadIdx.x >> 6;

  if (wid == 1) {
    // ============ DMA (2 ahead, dma-first) + out-write wave ============
    const float* xg = x + (size_t)b * SEQ * DS + lane * JPL;
    float* ob = out + (size_t)b * SEQ * DS;
    float al   = 1.0f / (1.0f + expf(-alph[0]));
    float dd   = expf(logd[0]);
    float coef = __builtin_fmaf(1.0f - al, dd, al);  // al + (1-al)*d
    float c1   = 1.0f - al;

    auto dma_blk = [&](int blk) {
      float* Xs = X[blk & 3];
#pragma unroll
      for (int u = 0; u < BLK; ++u) {
        const float* row = xg + (size_t)(blk * BLK + u) * DS;
        ld16(row,     Xs + u * 512);         // states [8l..8l+3] -> slots [4l..4l+3]
        ld16(row + 4, Xs + u * 512 + 256);   // states [8l+4..8l+7]
      }
    };
    auto out_blk = [&](int blk) {
      const float* SCs = (blk & 1) ? SC1 : SC0;
      const float* Xs  = X[blk & 3];
#pragma unroll
      for (int u = 0; u < BLK; ++u) {
        float s  = bcast63(wave_sum64(SCs[u * 64 + lane]));
        float sc = c1 * s;
        v4f xa = *(const v4f*)(Xs + u * 512 + lane * 4);
        v4f xb = *(const v4f*)(Xs + u * 512 + 256 + lane * 4);
        float* row = ob + (size_t)(blk * BLK + u) * DS + lane * 8;
        *(v4f*)(row)     = xa * coef + sc;
        *(v4f*)(row + 4) = xb * coef + sc;
      }
    };

    dma_blk(0);
    dma_blk(1);
    __syncthreads();  // B0 (drains vmcnt: blocks 0,1 sealed)
#pragma unroll 1
    for (int i = 0; i < NBLK; ++i) {
      // dma-first: buffers disjoint from out's ((i+2)&3 vs (i-1)&3), drain covered
      if (i + 2 < NBLK) dma_blk(i + 2);
      if (i >= 1) out_blk(i - 1);
      __syncthreads();
    }
    out_blk(NBLK - 1);
  } else if (wid == 2) {
    // ============ gate-reciprocal + c*bias*rg wave ============
    v2f gate[4];
#pragma unroll
    for (int j = 0; j < JPL; ++j)
      gate[j >> 1][j & 1] = 1.0f / (1.0f + expf(-vgat[lane * JPL + j]));
    v4f cb0, cb1;  // c*bias per state
#pragma unroll
    for (int m = 0; m < 4; ++m) {
      int n0 = lane * JPL + m, n1 = lane * JPL + 4 + m;
      cb0[m] = cvec[n0] * lnb[n0];
      cb1[m] = cvec[n1] * lnb[n1];
    }
    const float* vg = vol + (size_t)b * SEQ;

    auto rg_blk = [&](v4f Va, v4f Vb, float* Rs, float* SBs) {
#pragma unroll
      for (int u = 0; u < BLK; ++u) {
        float vt = (u < 4) ? Va[u] : Vb[u - 4];
        v4f r0, r1;
#pragma unroll
        for (int k = 0; k < 4; ++k) {
          v2f den = gate[k] * vt + 1.0f;
          float q0 = __builtin_amdgcn_rcpf(den.x);
          float q1 = __builtin_amdgcn_rcpf(den.y);
          if (k < 2) { r0[2 * k] = q0; r0[2 * k + 1] = q1; }
          else       { r1[2 * (k - 2)] = q0; r1[2 * (k - 2) + 1] = q1; }
        }
        *(v4f*)(Rs + u * 512 + lane * 4)       = r0;
        *(v4f*)(Rs + u * 512 + 256 + lane * 4) = r1;
        v4f md = cb0 * r0;
        md = __builtin_elementwise_fma(cb1, r1, md);
        v2f mh = lo2(md) + hi2(md);
        SBs[u * 64 + lane] = mh.x + mh.y;     // per-lane sum(c*bias*rg)
      }
    };

    {
      v4f V0a = *(const v4f*)(vg + 0), V0b = *(const v4f*)(vg + 4);
      rg_blk(V0a, V0b, G0, SB0);              // block 0
    }
    v4f VAa = *(const v4f*)(vg + 8),  VAb = *(const v4f*)(vg + 12);   // block 1
    v4f VBa = *(const v4f*)(vg + 16), VBb = *(const v4f*)(vg + 20);   // block 2
    __syncthreads();  // B0
#pragma unroll 1
    for (int i = 0; i < NBLK; ++i) {
      if (i + 1 < NBLK)
        rg_blk(VAa, VAb, (i & 1) ? G0 : G1, (i & 1) ? SB0 : SB1);  // block i+1
      VAa = VBa; VAb = VBb;
      if (i + 3 < NBLK) {
        VBa = *(const v4f*)(vg + (i + 3) * BLK);
        VBb = *(const v4f*)(vg + (i + 3) * BLK + 4);
      }
      __syncthreads();
    }
  } else {
    // ======================== consumer wave ========================
    v2f bd[4], aw[4], ab[4], cw[4];
#pragma unroll
    for (int j = 0; j < JPL; ++j) {
      int n = lane * JPL + j;
      float lam = -expf(llr[n]);
      float st  = expf(lstp[n]);
      float z   = st * lam;
      float ad  = (2.0f + z) / (2.0f - z);
      float bdv = st * (1.0f + ad) * expf(logb[n]) * 0.5f;
      float wv  = lnw[n], bi = lnb[n], cv = cvec[n];
      bd[j >> 1][j & 1] = bdv;
      aw[j >> 1][j & 1] = ad * wv;
      ab[j >> 1][j & 1] = ad * bi;
      cw[j >> 1][j & 1] = cv * wv;
    }
    // carried state
    v2f gP[4], wP[4];
    float invP, invP2, invP2x;
    v2f invPv;
    float sG, sGG, sGW, sW, sWW;

    __syncthreads();  // B0 (X block 0 sealed)
    {
      // init: hr_0 = bd*x_0 -> gP=0, wP=bd*x0, sums of wP reduced now
      v4f x00 = *(const v4f*)(X[0] + lane * 4);
      v4f x01 = *(const v4f*)(X[0] + 256 + lane * 4);
      v2f xv[4] = {lo2(x00), hi2(x00), lo2(x01), hi2(x01)};
#pragma unroll
      for (int k = 0; k < 4; ++k) { wP[k] = bd[k] * xv[k]; gP[k] = (v2f){0.0f, 0.0f}; }
      float sw0 = t4s(wP), sww0 = t4m(wP, wP);
      sW  = bcast63(wave_sum64(sw0));
      sWW = bcast63(wave_sum64(sww0));
      sG = 0.0f; sGG = 0.0f; sGW = 0.0f;
      invP = 0.0f; invP2 = 0.0f; invP2x = 0.0f;
      invPv = (v2f){0.0f, 0.0f};
    }

    auto proc_blk = [&](const float* Xs, const float* Xn, const float* Rs,
                        const float* SBs, float* SCs) {
#pragma unroll
      for (int u = 0; u < BLK; ++u) {
        // loads (off-spine)
        v4f rr0 = *(const v4f*)(Rs + u * 512 + lane * 4);
        v4f rr1 = *(const v4f*)(Rs + u * 512 + 256 + lane * 4);
        const float* xrow = (u < BLK - 1) ? (Xs + (u + 1) * 512) : Xn;  // x_{t+1}
        v4f xn0 = *(const v4f*)(xrow + lane * 4);
        v4f xn1 = *(const v4f*)(xrow + 256 + lane * 4);
        float u3s = SBs[u * 64 + lane];
        v2f rs[4]  = {lo2(rr0), hi2(rr0), lo2(rr1), hi2(rr1)};
        v2f xnv[4] = {lo2(xn0), hi2(xn0), lo2(xn1), hi2(xn1)};

        // pre-mu vector phase (prev-state only)
        v2f hr[4], q[4], wN[4];
#pragma unroll
        for (int k = 0; k < 4; ++k) {
          hr[k] = __builtin_elementwise_fma(invPv, gP[k], wP[k]);  // hr_t
          q[k]  = rs[k] * hr[k];
          v2f abrs = ab[k] * rs[k];
          wN[k] = __builtin_elementwise_fma(bd[k], xnv[k], abrs);  // w_t
        }
        // w-chains: mu-independent, issue early (fully hidden)
        float swn  = wave_sum64(t4s(wN));
        float swwn = wave_sum64(t4m(wN, wN));

        // scalar phase from PREV sums (spine)
        float S1 = __builtin_fmaf(invP, sG, sW);
        float S2 = __builtin_fmaf(invP2, sGG, __builtin_fmaf(invP2x, sGW, sWW));
        float mu  = S1 * (1.0f / DS);
        float m2e = __builtin_fmaf(S2, 1.0f / DS, LN_EPS);
        float var = __builtin_fmaf(-mu, mu, m2e);
        float inv = __builtin_amdgcn_rsqf(var);   // off-spine: consumed next step

        // post-mu (spine: tv -> g -> tree -> DPP)
        v2f muv = {mu, mu};
        v2f tv[4], g[4];
#pragma unroll
        for (int k = 0; k < 4; ++k) {
          tv[k] = __builtin_elementwise_fma(-muv, rs[k], q[k]);  // rs*(hr-mu)
          g[k]  = aw[k] * tv[k];
        }
        float sgn  = wave_sum64(t4s(g));
        float sggn = wave_sum64(t4m(g, g));
        float sgwn = wave_sum64(t4m(g, wN));

        // readout (off-spine)
        v2f u0 = cw[0] * tv[0];
        u0 = __builtin_elementwise_fma(cw[1], tv[1], u0);
        v2f u2 = cw[2] * tv[2];
        u2 = __builtin_elementwise_fma(cw[3], tv[3], u2);
        v2f uu = u0 + u2;
        float u1s = uu.x + uu.y;
        SCs[u * 64 + lane] = __builtin_fmaf(inv, u1s, u3s);

        // rotate state
        sG  = bcast63(sgn);
        sGG = bcast63(sggn);
        sGW = bcast63(sgwn);
        sW  = bcast63(swn);
        sWW = bcast63(swwn);
        invP = inv; invPv = (v2f){inv, inv};
        invP2 = inv * inv; invP2x = inv + inv;
#pragma unroll
        for (int k = 0; k < 4; ++k) { gP[k] = g[k]; wP[k] = wN[k]; }
      }
    };

#pragma unroll 1
    for (int i = 0; i < NBLK; ++i) {
      proc_blk(X[i & 3], X[(i + 1) & 3], (i & 1) ? G1 : G0,
               (i & 1) ? SB1 : SB0, (i & 1) ? SC1 : SC0);
      __syncthreads();
    }
  }
}

extern "C" void kernel_launch(void* const* d_in, const int* in_sizes, int n_in,
                              void* d_out, int out_size, void* d_ws, size_t ws_size,
                              hipStream_t stream) {
  const float* x    = (const float*)d_in[0];   // [8,4096,512]
  const float* vol  = (const float*)d_in[1];   // [8,4096,1]
  const float* llr  = (const float*)d_in[2];   // [512]
  const float* logb = (const float*)d_in[3];   // [512,1]
  const float* cvec = (const float*)d_in[4];   // [1,512]
  const float* logd = (const float*)d_in[5];   // [1]
  const float* lstp = (const float*)d_in[6];   // [512]
  const float* vgat = (const float*)d_in[7];   // [512]
  const float* alph = (const float*)d_in[8];   // [1]
  const float* lnw  = (const float*)d_in[9];   // [512]
  const float* lnb  = (const float*)d_in[10];  // [512]
  float* outf = (float*)d_out;

  ssm_scan<<<BATCH, 192, 0, stream>>>(x, vol, llr, logb, cvec, lstp,
                                      vgat, lnw, lnb, alph, logd, outf);
}